// Round 1
// baseline (423.942 us; speedup 1.0000x reference)
//
#include <hip/hip_runtime.h>
#include <hip/hip_bf16.h>

// ---------- types ----------
typedef __attribute__((ext_vector_type(8))) short bf16x8;   // 8 bf16 in 4 VGPRs
typedef __attribute__((ext_vector_type(4))) float f32x4;

__device__ inline unsigned short f2b(float x) {
  __hip_bfloat16 b = __float2bfloat16(x);
  return *reinterpret_cast<unsigned short*>(&b);
}

#define GAS(p) ((const __attribute__((address_space(1))) void*)(p))
#define LAS(p) ((__attribute__((address_space(3))) void*)(p))

// ---------- elementwise cast f32 -> bf16 (vectorized) ----------
__global__ __launch_bounds__(256) void cast_f32_bf16(const float* __restrict__ X,
                                                     unsigned short* __restrict__ Y, int n4) {
  int i = blockIdx.x * 256 + threadIdx.x;
  if (i < n4) {
    float4 v = reinterpret_cast<const float4*>(X)[i];
    ushort4 o;
    o.x = f2b(v.x); o.y = f2b(v.y); o.z = f2b(v.z); o.w = f2b(v.w);
    reinterpret_cast<ushort4*>(Y)[i] = o;
  }
}

// ---------- transpose + cast: W [K][N] f32 -> Wt [N][K] bf16 ----------
__global__ __launch_bounds__(256) void tcast(const float* __restrict__ W,
                                             unsigned short* __restrict__ Wt, int K, int N) {
  __shared__ float tile[32][33];
  int n0 = blockIdx.x * 32, k0 = blockIdx.y * 32;
  int tx = threadIdx.x & 31, ty = threadIdx.x >> 5;  // 32 x 8
#pragma unroll
  for (int i = 0; i < 32; i += 8)
    tile[ty + i][tx] = W[(size_t)(k0 + ty + i) * N + n0 + tx];
  __syncthreads();
#pragma unroll
  for (int i = 0; i < 32; i += 8)
    Wt[(size_t)(n0 + ty + i) * K + k0 + tx] = f2b(tile[tx][ty + i]);
}

// ---------- bf16 MFMA GEMM: C[M][N] = A[M][K] * Bt[N][K]^T, fp32 out ----------
// 128x128 tile, BK=32, 256 threads (4 waves, 2x2 wave grid, each wave 64x64).
__global__ __launch_bounds__(256) void gemm_bt(const unsigned short* __restrict__ A,
                                               const unsigned short* __restrict__ Bt,
                                               float* __restrict__ C, int M, int N, int K) {
  __shared__ unsigned short As[128 * 32];
  __shared__ unsigned short Bs[128 * 32];
  const int tid = threadIdx.x;
  const int w = tid >> 6, l = tid & 63;
  const int lr = l & 15, lg = l >> 4;
  const int wm = (w >> 1) << 6, wn = (w & 1) << 6;
  const size_t bm = (size_t)blockIdx.y * 128, bn = (size_t)blockIdx.x * 128;

  // staging map: thread t -> row t>>2 (64B rows of BK=32 bf16), col chunk (t&3)*8
  const int srow = tid >> 2;
  const int scol = (tid & 3) << 3;
  const unsigned short* Ag = A + (bm + srow) * (size_t)K + scol;
  const unsigned short* Bg = Bt + (bn + srow) * (size_t)K + scol;
  unsigned short* Al = As + w * 512;  // wave-uniform LDS base; HW adds lane*16B
  unsigned short* Bl = Bs + w * 512;

  f32x4 acc[4][4] = {};

  for (int k0 = 0; k0 < K; k0 += 32) {
    __syncthreads();
    __builtin_amdgcn_global_load_lds(GAS(Ag + k0), LAS(Al), 16, 0, 0);
    __builtin_amdgcn_global_load_lds(GAS(Ag + (size_t)64 * K + k0), LAS(Al + 2048), 16, 0, 0);
    __builtin_amdgcn_global_load_lds(GAS(Bg + k0), LAS(Bl), 16, 0, 0);
    __builtin_amdgcn_global_load_lds(GAS(Bg + (size_t)64 * K + k0), LAS(Bl + 2048), 16, 0, 0);
    __syncthreads();

    bf16x8 af[4], bfr[4];
#pragma unroll
    for (int mi = 0; mi < 4; ++mi)
      af[mi] = *reinterpret_cast<const bf16x8*>(&As[(wm + mi * 16 + lr) * 32 + lg * 8]);
#pragma unroll
    for (int ni = 0; ni < 4; ++ni)
      bfr[ni] = *reinterpret_cast<const bf16x8*>(&Bs[(wn + ni * 16 + lr) * 32 + lg * 8]);
#pragma unroll
    for (int mi = 0; mi < 4; ++mi)
#pragma unroll
      for (int ni = 0; ni < 4; ++ni)
        acc[mi][ni] = __builtin_amdgcn_mfma_f32_16x16x32_bf16(af[mi], bfr[ni], acc[mi][ni], 0, 0, 0);
  }

#pragma unroll
  for (int mi = 0; mi < 4; ++mi)
#pragma unroll
    for (int ni = 0; ni < 4; ++ni)
#pragma unroll
      for (int r = 0; r < 4; ++r) {
        size_t row = bm + wm + mi * 16 + lg * 4 + r;
        size_t col = bn + wn + ni * 16 + lr;
        C[row * N + col] = acc[mi][ni][r];
      }
}

// ---------- fused RMSNorm (over 2048) + RoPE, write bf16 q/k/v ----------
__global__ __launch_bounds__(256) void rms_rope(const float* __restrict__ qkv,
                                                const int* __restrict__ pos,
                                                const float* __restrict__ qw,
                                                const float* __restrict__ kw,
                                                unsigned short* __restrict__ qb,
                                                unsigned short* __restrict__ kb,
                                                unsigned short* __restrict__ vb) {
  const int t = blockIdx.x;
  const float* row = qkv + (size_t)t * 6144;
  __shared__ float redq[4], redk[4];
  __shared__ float cs[64], sn[64];
  const int tid = threadIdx.x, w = tid >> 6, l = tid & 63;

  float sq = 0.f, sk = 0.f;
#pragma unroll
  for (int i = 0; i < 8; ++i) {
    float a = row[tid + i * 256]; sq += a * a;
    float b = row[2048 + tid + i * 256]; sk += b * b;
  }
#pragma unroll
  for (int m = 32; m >= 1; m >>= 1) { sq += __shfl_xor(sq, m, 64); sk += __shfl_xor(sk, m, 64); }
  if (l == 0) { redq[w] = sq; redk[w] = sk; }
  if (tid < 64) {
    // inv_freq = theta^(-j/64) = exp2(-j * log2(1e6)/64)
    float fr = exp2f(-(float)tid * 0.31143075889569016f);
    float ang = (float)pos[t] * fr;
    cs[tid] = cosf(ang);
    sn[tid] = sinf(ang);
  }
  __syncthreads();
  float rq = rsqrtf((redq[0] + redq[1] + redq[2] + redq[3]) * (1.f / 2048.f) + 1e-5f);
  float rk = rsqrtf((redk[0] + redk[1] + redk[2] + redk[3]) * (1.f / 2048.f) + 1e-5f);

  unsigned short* qo = qb + (size_t)t * 2048;
  unsigned short* ko = kb + (size_t)t * 2048;
  unsigned short* vo = vb + (size_t)t * 2048;
#pragma unroll
  for (int pp = 0; pp < 4; ++pp) {
    int pr = tid + pp * 256;  // pair index 0..1023
    int h = pr >> 6, j = pr & 63;
    int b0 = h * 128 + j;
    float c = cs[j], s = sn[j];
    float x1 = row[b0] * rq * qw[b0];
    float x2 = row[b0 + 64] * rq * qw[b0 + 64];
    qo[b0]      = f2b(x1 * c - x2 * s);
    qo[b0 + 64] = f2b(x2 * c + x1 * s);
    float y1 = row[2048 + b0] * rk * kw[b0];
    float y2 = row[2048 + b0 + 64] * rk * kw[b0 + 64];
    ko[b0]      = f2b(y1 * c - y2 * s);
    ko[b0 + 64] = f2b(y2 * c + y1 * s);
  }
#pragma unroll
  for (int i = 0; i < 8; ++i) vo[tid + i * 256] = f2b(row[4096 + tid + i * 256]);
}

// ---------- causal flash attention, bf16 MFMA ----------
// block = 256 thr (4 waves), handles (head, 64 q-rows); wave w -> 16 q-rows.
// 32-key tiles: K staged [32][132] (padded), V staged transposed [128][34].
__global__ __launch_bounds__(256) void attn_fwd(const unsigned short* __restrict__ qb,
                                                const unsigned short* __restrict__ kb,
                                                const unsigned short* __restrict__ vb,
                                                unsigned short* __restrict__ ob) {
  __shared__ unsigned short Ks[32 * 132];
  __shared__ unsigned short Vt[128 * 34];
  __shared__ unsigned short Ps[4][16 * 32];
  const int h = blockIdx.y;
  const int q0 = blockIdx.x * 64;
  const int tid = threadIdx.x, w = tid >> 6, l = tid & 63;
  const int lr = l & 15, lg = l >> 4;

  bf16x8 qf[4];
  {
    const unsigned short* qp = qb + (size_t)(q0 + w * 16 + lr) * 2048 + h * 128;
#pragma unroll
    for (int kc = 0; kc < 4; ++kc)
      qf[kc] = *reinterpret_cast<const bf16x8*>(qp + kc * 32 + lg * 8);
  }
  f32x4 oacc[8] = {};
  float mrow[4], lrow[4];
#pragma unroll
  for (int r = 0; r < 4; ++r) { mrow[r] = -1e30f; lrow[r] = 0.f; }

  const int skk = tid >> 3, sdc = (tid & 7) * 16;
  const float scale = 0.08838834764831845f;  // 1/sqrt(128)

  for (int k0 = 0; k0 < q0 + 64; k0 += 32) {
    __syncthreads();
    {
      const unsigned short* ksrc = kb + (size_t)(k0 + skk) * 2048 + h * 128 + sdc;
      bf16x8 a0 = *reinterpret_cast<const bf16x8*>(ksrc);
      bf16x8 a1 = *reinterpret_cast<const bf16x8*>(ksrc + 8);
      *reinterpret_cast<bf16x8*>(&Ks[skk * 132 + sdc]) = a0;
      *reinterpret_cast<bf16x8*>(&Ks[skk * 132 + sdc + 8]) = a1;
      const unsigned short* vsrc = vb + (size_t)(k0 + skk) * 2048 + h * 128 + sdc;
      bf16x8 u0 = *reinterpret_cast<const bf16x8*>(vsrc);
      bf16x8 u1 = *reinterpret_cast<const bf16x8*>(vsrc + 8);
#pragma unroll
      for (int j = 0; j < 8; ++j) Vt[(sdc + j) * 34 + skk] = (unsigned short)u0[j];
#pragma unroll
      for (int j = 0; j < 8; ++j) Vt[(sdc + 8 + j) * 34 + skk] = (unsigned short)u1[j];
    }
    __syncthreads();

    // S = Q K^T : two 16-key column groups
    f32x4 s0 = {}, s1 = {};
#pragma unroll
    for (int kc = 0; kc < 4; ++kc) {
      bf16x8 b0 = *reinterpret_cast<const bf16x8*>(&Ks[lr * 132 + kc * 32 + lg * 8]);
      bf16x8 b1 = *reinterpret_cast<const bf16x8*>(&Ks[(16 + lr) * 132 + kc * 32 + lg * 8]);
      s0 = __builtin_amdgcn_mfma_f32_16x16x32_bf16(qf[kc], b0, s0, 0, 0, 0);
      s1 = __builtin_amdgcn_mfma_f32_16x16x32_bf16(qf[kc], b1, s1, 0, 0, 0);
    }

    // online softmax per q-row (row = lg*4 + r, col = lr / 16+lr)
#pragma unroll
    for (int r = 0; r < 4; ++r) {
      int qr = q0 + w * 16 + lg * 4 + r;
      float a = s0[r] * scale; if (k0 + lr > qr)      a = -1e30f;
      float b = s1[r] * scale; if (k0 + 16 + lr > qr) b = -1e30f;
      float mx = fmaxf(a, b);
#pragma unroll
      for (int m = 8; m >= 1; m >>= 1) mx = fmaxf(mx, __shfl_xor(mx, m, 16));
      float mnew = fmaxf(mrow[r], mx);
      float corr = __expf(mrow[r] - mnew);
      float pa = __expf(a - mnew), pb = __expf(b - mnew);
      float ps = pa + pb;
#pragma unroll
      for (int m = 8; m >= 1; m >>= 1) ps += __shfl_xor(ps, m, 16);
      lrow[r] = lrow[r] * corr + ps;
      mrow[r] = mnew;
#pragma unroll
      for (int ni = 0; ni < 8; ++ni) oacc[ni][r] *= corr;
      Ps[w][(lg * 4 + r) * 32 + lr] = f2b(pa);
      Ps[w][(lg * 4 + r) * 32 + 16 + lr] = f2b(pb);
    }

    // O += P V
    bf16x8 pf = *reinterpret_cast<const bf16x8*>(&Ps[w][lr * 32 + lg * 8]);
#pragma unroll
    for (int ni = 0; ni < 8; ++ni) {
      bf16x8 vf = *reinterpret_cast<const bf16x8*>(&Vt[(ni * 16 + lr) * 34 + lg * 8]);
      oacc[ni] = __builtin_amdgcn_mfma_f32_16x16x32_bf16(pf, vf, oacc[ni], 0, 0, 0);
    }
  }

#pragma unroll
  for (int ni = 0; ni < 8; ++ni)
#pragma unroll
    for (int r = 0; r < 4; ++r) {
      int qr = q0 + w * 16 + lg * 4 + r;
      ob[(size_t)qr * 2048 + h * 128 + ni * 16 + lr] = f2b(oacc[ni][r] / lrow[r]);
    }
}

// ---------- launch ----------
extern "C" void kernel_launch(void* const* d_in, const int* in_sizes, int n_in,
                              void* d_out, int out_size, void* d_ws, size_t ws_size,
                              hipStream_t stream) {
  const float* hs   = (const float*)d_in[0];
  const int*   pos  = (const int*)d_in[1];
  const float* wqkv = (const float*)d_in[2];
  const float* qnw  = (const float*)d_in[3];
  const float* knw  = (const float*)d_in[4];
  const float* wo   = (const float*)d_in[5];
  float* out = (float*)d_out;

  char* ws = (char*)d_ws;
  size_t off = 0;
  auto take = [&](size_t bytes) {
    char* p = ws + off;
    off = (off + bytes + 255) & ~(size_t)255;
    return p;
  };
  unsigned short* hidA  = (unsigned short*)take(2048ull * 2048 * 2);
  unsigned short* wqkvT = (unsigned short*)take(6144ull * 2048 * 2);
  unsigned short* woT   = (unsigned short*)take(2048ull * 2048 * 2);
  float*          qkvF  = (float*)take(2048ull * 6144 * 4);
  unsigned short* qbv   = (unsigned short*)take(2048ull * 2048 * 2);
  unsigned short* kbv   = (unsigned short*)take(2048ull * 2048 * 2);
  unsigned short* vbv   = (unsigned short*)take(2048ull * 2048 * 2);
  unsigned short* attnb = (unsigned short*)take(2048ull * 2048 * 2);

  cast_f32_bf16<<<4096, 256, 0, stream>>>(hs, hidA, 1048576);
  tcast<<<dim3(192, 64), 256, 0, stream>>>(wqkv, wqkvT, 2048, 6144);
  tcast<<<dim3(64, 64), 256, 0, stream>>>(wo, woT, 2048, 2048);
  gemm_bt<<<dim3(48, 16), 256, 0, stream>>>(hidA, wqkvT, qkvF, 2048, 6144, 2048);
  rms_rope<<<2048, 256, 0, stream>>>(qkvF, pos, qnw, knw, qbv, kbv, vbv);
  attn_fwd<<<dim3(32, 16), 256, 0, stream>>>(qbv, kbv, vbv, attnb);
  gemm_bt<<<dim3(16, 16), 256, 0, stream>>>(attnb, woT, out, 2048, 2048, 2048);
}

// Round 3
// 362.586 us; speedup vs baseline: 1.1692x; 1.1692x over previous
//
#include <hip/hip_runtime.h>
#include <hip/hip_bf16.h>

// ---------- types ----------
typedef __attribute__((ext_vector_type(8))) short bf16x8;   // 8 bf16 in 4 VGPRs
typedef __attribute__((ext_vector_type(4))) float f32x4;

__device__ inline unsigned short f2b(float x) {
  __hip_bfloat16 b = __float2bfloat16(x);
  return *reinterpret_cast<unsigned short*>(&b);
}
__device__ inline float b2f(unsigned short u) {
  return __bfloat162float(*reinterpret_cast<const __hip_bfloat16*>(&u));
}

#define GAS(p) ((const __attribute__((address_space(1))) void*)(p))
#define LAS(p) ((__attribute__((address_space(3))) void*)(p))

// ---------- elementwise cast f32 -> bf16 (vectorized) ----------
__global__ __launch_bounds__(256) void cast_f32_bf16(const float* __restrict__ X,
                                                     unsigned short* __restrict__ Y, int n4) {
  int i = blockIdx.x * 256 + threadIdx.x;
  if (i < n4) {
    float4 v = reinterpret_cast<const float4*>(X)[i];
    ushort4 o;
    o.x = f2b(v.x); o.y = f2b(v.y); o.z = f2b(v.z); o.w = f2b(v.w);
    reinterpret_cast<ushort4*>(Y)[i] = o;
  }
}

// ---------- transpose + cast: W [K][N] f32 -> Wt [N][K] bf16 ----------
__global__ __launch_bounds__(256) void tcast(const float* __restrict__ W,
                                             unsigned short* __restrict__ Wt, int K, int N) {
  __shared__ float tile[32][33];
  int n0 = blockIdx.x * 32, k0 = blockIdx.y * 32;
  int tx = threadIdx.x & 31, ty = threadIdx.x >> 5;  // 32 x 8
#pragma unroll
  for (int i = 0; i < 32; i += 8)
    tile[ty + i][tx] = W[(size_t)(k0 + ty + i) * N + n0 + tx];
  __syncthreads();
#pragma unroll
  for (int i = 0; i < 32; i += 8)
    Wt[(size_t)(n0 + ty + i) * K + k0 + tx] = f2b(tile[tx][ty + i]);
}

// ---------- V transpose+cast: qkvF[:,4096+c] f32 -> Vt[c][t] bf16 ----------
__global__ __launch_bounds__(256) void vtrans(const float* __restrict__ qkv,
                                              unsigned short* __restrict__ Vt) {
  __shared__ unsigned short tile[32][33];
  int c0 = blockIdx.x * 32;  // hd dim
  int t0 = blockIdx.y * 32;  // token dim
  int tx = threadIdx.x & 31, ty = threadIdx.x >> 5;  // 32 x 8
#pragma unroll
  for (int i = 0; i < 32; i += 8)
    tile[ty + i][tx] = f2b(qkv[(size_t)(t0 + ty + i) * 6144 + 4096 + c0 + tx]);
  __syncthreads();
#pragma unroll
  for (int i = 0; i < 32; i += 8)
    Vt[(size_t)(c0 + ty + i) * 2048 + t0 + tx] = tile[tx][ty + i];
}

// ---------- bf16 MFMA GEMM: C[M][N] = A[M][K] * Bt[N][K]^T, fp32 out ----------
// 128x128 tile, BK=32, 256 threads (4 waves, 2x2 wave grid, each wave 64x64).
__global__ __launch_bounds__(256) void gemm_bt(const unsigned short* __restrict__ A,
                                               const unsigned short* __restrict__ Bt,
                                               float* __restrict__ C, int M, int N, int K) {
  __shared__ unsigned short As[128 * 32];
  __shared__ unsigned short Bs[128 * 32];
  const int tid = threadIdx.x;
  const int w = tid >> 6, l = tid & 63;
  const int lr = l & 15, lg = l >> 4;
  const int wm = (w >> 1) << 6, wn = (w & 1) << 6;
  const size_t bm = (size_t)blockIdx.y * 128, bn = (size_t)blockIdx.x * 128;

  const int srow = tid >> 2;
  const int scol = (tid & 3) << 3;
  const unsigned short* Ag = A + (bm + srow) * (size_t)K + scol;
  const unsigned short* Bg = Bt + (bn + srow) * (size_t)K + scol;
  unsigned short* Al = As + w * 512;   // wave-uniform LDS base; HW adds lane*16B
  unsigned short* Bl = Bs + w * 512;

  f32x4 acc[4][4] = {};

  for (int k0 = 0; k0 < K; k0 += 32) {
    __syncthreads();
    __builtin_amdgcn_global_load_lds(GAS(Ag + k0), LAS(Al), 16, 0, 0);
    __builtin_amdgcn_global_load_lds(GAS(Ag + (size_t)64 * K + k0), LAS(Al + 2048), 16, 0, 0);
    __builtin_amdgcn_global_load_lds(GAS(Bg + k0), LAS(Bl), 16, 0, 0);
    __builtin_amdgcn_global_load_lds(GAS(Bg + (size_t)64 * K + k0), LAS(Bl + 2048), 16, 0, 0);
    __syncthreads();

    bf16x8 af[4], bfr[4];
#pragma unroll
    for (int mi = 0; mi < 4; ++mi)
      af[mi] = *reinterpret_cast<const bf16x8*>(&As[(wm + mi * 16 + lr) * 32 + lg * 8]);
#pragma unroll
    for (int ni = 0; ni < 4; ++ni)
      bfr[ni] = *reinterpret_cast<const bf16x8*>(&Bs[(wn + ni * 16 + lr) * 32 + lg * 8]);
#pragma unroll
    for (int mi = 0; mi < 4; ++mi)
#pragma unroll
      for (int ni = 0; ni < 4; ++ni)
        acc[mi][ni] = __builtin_amdgcn_mfma_f32_16x16x32_bf16(af[mi], bfr[ni], acc[mi][ni], 0, 0, 0);
  }

#pragma unroll
  for (int mi = 0; mi < 4; ++mi)
#pragma unroll
    for (int ni = 0; ni < 4; ++ni)
#pragma unroll
      for (int r = 0; r < 4; ++r) {
        size_t row = bm + wm + mi * 16 + lg * 4 + r;
        size_t col = bn + wn + ni * 16 + lr;
        C[row * N + col] = acc[mi][ni][r];
      }
}

// ---------- fused RMSNorm (over 2048) + RoPE, write bf16 q/k ----------
__global__ __launch_bounds__(256) void rms_rope(const float* __restrict__ qkv,
                                                const int* __restrict__ pos,
                                                const float* __restrict__ qw,
                                                const float* __restrict__ kw,
                                                unsigned short* __restrict__ qb,
                                                unsigned short* __restrict__ kb) {
  const int t = blockIdx.x;
  const float* row = qkv + (size_t)t * 6144;
  __shared__ float redq[4], redk[4];
  __shared__ float cs[64], sn[64];
  const int tid = threadIdx.x, w = tid >> 6, l = tid & 63;

  float sq = 0.f, sk = 0.f;
#pragma unroll
  for (int i = 0; i < 8; ++i) {
    float a = row[tid + i * 256]; sq += a * a;
    float b = row[2048 + tid + i * 256]; sk += b * b;
  }
#pragma unroll
  for (int m = 32; m >= 1; m >>= 1) { sq += __shfl_xor(sq, m, 64); sk += __shfl_xor(sk, m, 64); }
  if (l == 0) { redq[w] = sq; redk[w] = sk; }
  if (tid < 64) {
    float fr = exp2f(-(float)tid * 0.31143075889569016f);  // theta^(-j/64)
    float ang = (float)pos[t] * fr;
    cs[tid] = cosf(ang);
    sn[tid] = sinf(ang);
  }
  __syncthreads();
  float rq = rsqrtf((redq[0] + redq[1] + redq[2] + redq[3]) * (1.f / 2048.f) + 1e-5f);
  float rk = rsqrtf((redk[0] + redk[1] + redk[2] + redk[3]) * (1.f / 2048.f) + 1e-5f);

  unsigned short* qo = qb + (size_t)t * 2048;
  unsigned short* ko = kb + (size_t)t * 2048;
#pragma unroll
  for (int pp = 0; pp < 4; ++pp) {
    int pr = tid + pp * 256;  // pair index 0..1023
    int h = pr >> 6, j = pr & 63;
    int b0 = h * 128 + j;
    float c = cs[j], s = sn[j];
    float x1 = row[b0] * rq * qw[b0];
    float x2 = row[b0 + 64] * rq * qw[b0 + 64];
    qo[b0]      = f2b(x1 * c - x2 * s);
    qo[b0 + 64] = f2b(x2 * c + x1 * s);
    float y1 = row[2048 + b0] * rk * kw[b0];
    float y2 = row[2048 + b0 + 64] * rk * kw[b0 + 64];
    ko[b0]      = f2b(y1 * c - y2 * s);
    ko[b0 + 64] = f2b(y2 * c + y1 * s);
  }
}

// ---------- causal flash attention, K-split partials ----------
// grid (32 qtiles, 16 heads, 4 splits of 512 keys), 256 thr (4 waves x 16 q-rows).
// KVBLK=64. K staged [64][128] via global_load_lds with 16B-chunk XOR swizzle
// (linear LDS dest + inverse-swizzled global src + swizzled read — rule #21);
// V^T staged [128][64] same way. P per-wave [16][72] (padded stride).
__global__ __launch_bounds__(256) void attn_part(const unsigned short* __restrict__ qb,
                                                 const unsigned short* __restrict__ kb,
                                                 const unsigned short* __restrict__ vt,
                                                 unsigned short* __restrict__ Op,
                                                 float* __restrict__ ml) {
  __shared__ unsigned short Ks[64 * 128];   // [key][d], swizzled chunks
  __shared__ unsigned short Vs[128 * 64];   // [d][key], swizzled chunks
  __shared__ unsigned short Ps[4][16 * 72];
  const int qt = blockIdx.x, h = blockIdx.y, sp = blockIdx.z;
  const int q0 = qt * 64;
  const int kbeg = sp * 512;
  if (kbeg >= q0 + 64) return;
  const int kend = min(kbeg + 512, q0 + 64);
  const int tid = threadIdx.x, w = tid >> 6, l = tid & 63;
  const int lr = l & 15, lg = l >> 4;
  const float scale = 0.08838834764831845f;  // 1/sqrt(128)

  bf16x8 qf[4];
  {
    const unsigned short* qp = qb + (size_t)(q0 + w * 16 + lr) * 2048 + h * 128;
#pragma unroll
    for (int kc = 0; kc < 4; ++kc)
      qf[kc] = *reinterpret_cast<const bf16x8*>(qp + kc * 32 + lg * 8);
  }
  f32x4 oacc[8] = {};
  float mrow[4], lrow[4];
#pragma unroll
  for (int r = 0; r < 4; ++r) { mrow[r] = -1e30f; lrow[r] = 0.f; }

  for (int k0 = kbeg; k0 < kend; k0 += 64) {
    __syncthreads();
    {  // stage K: wave w covers rows w*16 .. w*16+15 (4 rows / call)
      const int r0 = l >> 4, cph = l & 15;
#pragma unroll
      for (int rb = 0; rb < 16; rb += 4) {
        int row = w * 16 + rb + r0;
        int clog = (cph & 8) | ((cph & 7) ^ (row & 7));
        const unsigned short* src = kb + (size_t)(k0 + row) * 2048 + h * 128 + clog * 8;
        __builtin_amdgcn_global_load_lds(GAS(src), LAS((char*)Ks + (w * 16 + rb) * 256), 16, 0, 0);
      }
      // stage V^T: wave w covers rows w*32 .. w*32+31 (8 rows / call)
      const int r0v = l >> 3, cpv = l & 7;
#pragma unroll
      for (int rb = 0; rb < 32; rb += 8) {
        int row = w * 32 + rb + r0v;
        int clog = cpv ^ (row & 7);
        const unsigned short* src = vt + (size_t)(h * 128 + row) * 2048 + k0 + clog * 8;
        __builtin_amdgcn_global_load_lds(GAS(src), LAS((char*)Vs + (w * 32 + rb) * 128), 16, 0, 0);
      }
    }
    __syncthreads();

    // S = Q K^T : 4 column groups of 16 keys
    f32x4 s[4] = {};
#pragma unroll
    for (int kc = 0; kc < 4; ++kc)
#pragma unroll
      for (int cg = 0; cg < 4; ++cg) {
        int key = cg * 16 + lr;
        int c = 4 * kc + lg;
        int cswz = (c & 8) | ((c & 7) ^ (key & 7));
        bf16x8 kf = *reinterpret_cast<const bf16x8*>(&Ks[key * 128 + cswz * 8]);
        s[cg] = __builtin_amdgcn_mfma_f32_16x16x32_bf16(qf[kc], kf, s[cg], 0, 0, 0);
      }

    // online softmax per q-row (row = lg*4 + r; 16 lanes share a row)
#pragma unroll
    for (int r = 0; r < 4; ++r) {
      const int qr = q0 + w * 16 + lg * 4 + r;
      float pv[4]; bool msk[4];
      float mx = -1e30f;
#pragma unroll
      for (int cg = 0; cg < 4; ++cg) {
        msk[cg] = (k0 + cg * 16 + lr) > qr;
        float v = msk[cg] ? -1e30f : s[cg][r] * scale;
        pv[cg] = v;
        mx = fmaxf(mx, v);
      }
#pragma unroll
      for (int m = 8; m >= 1; m >>= 1) mx = fmaxf(mx, __shfl_xor(mx, m, 16));
      float mnew = fmaxf(mrow[r], mx);
      float corr = __expf(mrow[r] - mnew);
      float ps = 0.f;
#pragma unroll
      for (int cg = 0; cg < 4; ++cg) {
        float pe = msk[cg] ? 0.f : __expf(pv[cg] - mnew);
        pv[cg] = pe; ps += pe;
      }
#pragma unroll
      for (int m = 8; m >= 1; m >>= 1) ps += __shfl_xor(ps, m, 16);
      lrow[r] = lrow[r] * corr + ps;
      mrow[r] = mnew;
#pragma unroll
      for (int ni = 0; ni < 8; ++ni) oacc[ni][r] *= corr;
#pragma unroll
      for (int cg = 0; cg < 4; ++cg)
        Ps[w][(lg * 4 + r) * 72 + cg * 16 + lr] = f2b(pv[cg]);
    }

    // O += P V  (wave-internal LDS dep on Ps; no barrier needed)
#pragma unroll
    for (int ks = 0; ks < 2; ++ks) {
      bf16x8 pf = *reinterpret_cast<const bf16x8*>(&Ps[w][lr * 72 + ks * 32 + lg * 8]);
#pragma unroll
      for (int ni = 0; ni < 8; ++ni) {
        int d = ni * 16 + lr;
        int c = ks * 4 + lg;
        int cswz = c ^ (d & 7);
        bf16x8 vf = *reinterpret_cast<const bf16x8*>(&Vs[d * 64 + cswz * 8]);
        oacc[ni] = __builtin_amdgcn_mfma_f32_16x16x32_bf16(pf, vf, oacc[ni], 0, 0, 0);
      }
    }
  }

  // epilogue: unnormalized partial O (bf16) + per-row m,l
  const size_t base = (((size_t)sp * 16 + h) * 32 + qt) * 64;
#pragma unroll
  for (int ni = 0; ni < 8; ++ni)
#pragma unroll
    for (int r = 0; r < 4; ++r)
      Op[(base + w * 16 + lg * 4 + r) * 128 + ni * 16 + lr] = f2b(oacc[ni][r]);
  if (lr == 0) {
#pragma unroll
    for (int r = 0; r < 4; ++r) {
      size_t mi = (base + w * 16 + lg * 4 + r) * 2;
      ml[mi] = mrow[r]; ml[mi + 1] = lrow[r];
    }
  }
}

// ---------- combine K-split partials (static indexing — rule #20) ----------
__global__ __launch_bounds__(256) void attn_combine(const unsigned short* __restrict__ Op,
                                                    const float* __restrict__ ml,
                                                    unsigned short* __restrict__ ob) {
  const int qt = blockIdx.x, h = blockIdx.y;
  const int q0 = qt * 64;
  const int ns = q0 / 512 + 1;  // 1..4 valid splits
  const int t = threadIdx.x;
  const int row = t >> 2, dp = (t & 3) * 32;

  float m_s[4], l_s[4];
  float M = -1e30f;
#pragma unroll
  for (int s = 0; s < 4; ++s) {
    if (s < ns) {
      size_t mi = ((((size_t)s * 16 + h) * 32 + qt) * 64 + row) * 2;
      m_s[s] = ml[mi]; l_s[s] = ml[mi + 1];
    } else { m_s[s] = -1e30f; l_s[s] = 0.f; }
    M = fmaxf(M, m_s[s]);
  }
  float L = 0.f, wgt[4];
#pragma unroll
  for (int s = 0; s < 4; ++s) { wgt[s] = __expf(m_s[s] - M); L += l_s[s] * wgt[s]; }
  float invL = 1.f / L;

  float acc[32];
#pragma unroll
  for (int j = 0; j < 32; ++j) acc[j] = 0.f;
#pragma unroll
  for (int s = 0; s < 4; ++s) {
    if (s < ns) {
      const unsigned short* op = Op + ((((size_t)s * 16 + h) * 32 + qt) * 64 + row) * 128 + dp;
      float wg = wgt[s] * invL;
#pragma unroll
      for (int j = 0; j < 32; j += 8) {
        bf16x8 v = *reinterpret_cast<const bf16x8*>(op + j);
#pragma unroll
        for (int e = 0; e < 8; ++e) acc[j + e] += wg * b2f((unsigned short)v[e]);
      }
    }
  }
  unsigned short* o = ob + (size_t)(q0 + row) * 2048 + h * 128 + dp;
#pragma unroll
  for (int j = 0; j < 32; ++j) o[j] = f2b(acc[j]);
}

// ---------- launch ----------
extern "C" void kernel_launch(void* const* d_in, const int* in_sizes, int n_in,
                              void* d_out, int out_size, void* d_ws, size_t ws_size,
                              hipStream_t stream) {
  const float* hs   = (const float*)d_in[0];
  const int*   pos  = (const int*)d_in[1];
  const float* wqkv = (const float*)d_in[2];
  const float* qnw  = (const float*)d_in[3];
  const float* knw  = (const float*)d_in[4];
  const float* wo   = (const float*)d_in[5];
  float* out = (float*)d_out;

  char* ws = (char*)d_ws;
  size_t off = 0;
  auto take = [&](size_t bytes) {
    char* p = ws + off;
    off = (off + bytes + 255) & ~(size_t)255;
    return p;
  };
  unsigned short* hidA  = (unsigned short*)take(2048ull * 2048 * 2);
  unsigned short* wqkvT = (unsigned short*)take(6144ull * 2048 * 2);
  unsigned short* woT   = (unsigned short*)take(2048ull * 2048 * 2);
  float*          qkvF  = (float*)take(2048ull * 6144 * 4);
  unsigned short* qbv   = (unsigned short*)take(2048ull * 2048 * 2);
  unsigned short* kbv   = (unsigned short*)take(2048ull * 2048 * 2);
  unsigned short* vtb   = (unsigned short*)take(2048ull * 2048 * 2);
  unsigned short* attnb = (unsigned short*)take(2048ull * 2048 * 2);
  // aliases over qkvF (dead after rms_rope + vtrans):
  unsigned short* Opart = (unsigned short*)qkvF;                         // 32 MiB
  float*          mlb   = (float*)((char*)qkvF + 32ull * 1024 * 1024);   // 2 MiB

  cast_f32_bf16<<<4096, 256, 0, stream>>>(hs, hidA, 1048576);
  tcast<<<dim3(192, 64), 256, 0, stream>>>(wqkv, wqkvT, 2048, 6144);
  tcast<<<dim3(64, 64), 256, 0, stream>>>(wo, woT, 2048, 2048);
  gemm_bt<<<dim3(48, 16), 256, 0, stream>>>(hidA, wqkvT, qkvF, 2048, 6144, 2048);
  rms_rope<<<2048, 256, 0, stream>>>(qkvF, pos, qnw, knw, qbv, kbv);
  vtrans<<<dim3(64, 64), 256, 0, stream>>>(qkvF, vtb);
  attn_part<<<dim3(32, 16, 4), 256, 0, stream>>>(qbv, kbv, vtb, Opart, mlb);
  attn_combine<<<dim3(32, 16), 256, 0, stream>>>(Opart, mlb, attnb);
  gemm_bt<<<dim3(16, 16), 256, 0, stream>>>(attnb, woT, out, 2048, 2048, 2048);
}